// Round 1
// baseline (765.825 us; speedup 1.0000x reference)
//
#include <hip/hip_runtime.h>
#include <cstdint>

#define B_ 16384
#define S_ 1024
#define L_ 256
#define K_ 4096
#define H_ 64

__device__ __forceinline__ unsigned int f2ord(float f) {
  unsigned int u = __float_as_uint(f);
  return (u & 0x80000000u) ? ~u : (u | 0x80000000u);
}

__device__ __forceinline__ void fma16(const float a[4], const float b[4], float acc[4][4]) {
#pragma unroll
  for (int ii = 0; ii < 4; ++ii)
#pragma unroll
    for (int jj = 0; jj < 4; ++jj)
      acc[ii][jj] = fmaf(a[ii], b[jj], acc[ii][jj]);
}

// ---------------- K0a: wnorm[c] = ||emb[c]||^2 ----------------
// grid K_/4 blocks x 256 threads (4 waves, one code per wave)
__global__ __launch_bounds__(256)
void wnorm_kernel(const float* __restrict__ emb, float* __restrict__ wnorm) {
  const int lane = threadIdx.x & 63, wv = threadIdx.x >> 6;
  const int c = blockIdx.x * 4 + wv;
  const float4 v = *(const float4*)(emb + (long)c * L_ + (lane << 2));
  float s = v.x * v.x + v.y * v.y + v.z * v.z + v.w * v.w;
#pragma unroll
  for (int off = 32; off > 0; off >>= 1) s += __shfl_down(s, off, 64);
  if (lane == 0) wnorm[c] = s;
}

// ---------------- K0b: embT[l][c] = emb[c][l] ----------------
// grid (K_/64, L_/64) x 256 threads
__global__ __launch_bounds__(256)
void tr_emb_kernel(const float* __restrict__ emb, float* __restrict__ embT) {
  __shared__ float tile[64][68];
  const int t = threadIdx.x;
  const int a = t & 63, q = t >> 6;
  const int c0 = blockIdx.x * 64, l0 = blockIdx.y * 64;
#pragma unroll
  for (int i = 0; i < 4; ++i) {
    const int lq = q * 16 + i * 4;
    *(float4*)&tile[a][lq] = *(const float4*)(emb + (long)(c0 + a) * L_ + l0 + lq);
  }
  __syncthreads();
  const int cx = t & 15, ly = t >> 4;
#pragma unroll
  for (int i = 0; i < 4; ++i) {
    const int l = i * 16 + ly;
    float4 w;
    w.x = tile[(cx << 2) + 0][l];
    w.y = tile[(cx << 2) + 1][l];
    w.z = tile[(cx << 2) + 2][l];
    w.w = tile[(cx << 2) + 3][l];
    *(float4*)(embT + (long)(l0 + l) * K_ + c0 + (cx << 2)) = w;
  }
}

// ---------------- K1: h = relu(x @ w1 + b1) ----------------
// grid B_/64 x 256
__global__ __launch_bounds__(256)
void enc1_kernel(const float* __restrict__ x, const float* __restrict__ w1,
                 const float* __restrict__ b1, float* __restrict__ h) {
  __shared__ float xs[64][64];   // [r][k]
  __shared__ float ws[64][64];   // [k][c]
  const int t = threadIdx.x;
  const int tx = t & 15, ty = t >> 4;
  const long row0 = (long)blockIdx.x * 64;
  float acc[4][4] = {};
  for (int k0 = 0; k0 < S_; k0 += 64) {
#pragma unroll
    for (int i = 0; i < 4; ++i) {
      const int r = ty + 16 * i;
      *(float4*)&xs[r][tx << 2] = *(const float4*)(x + (row0 + r) * S_ + k0 + (tx << 2));
    }
#pragma unroll
    for (int i = 0; i < 4; ++i) {
      const int g = (i << 8) + t;
      const int kk = g >> 4, c = (g & 15) << 2;
      *(float4*)&ws[kk][c] = *(const float4*)(w1 + (long)(k0 + kk) * H_ + c);
    }
    __syncthreads();
#pragma unroll 4
    for (int k = 0; k < 64; ++k) {
      float a[4], b[4];
#pragma unroll
      for (int ii = 0; ii < 4; ++ii) a[ii] = xs[(ty << 2) + ii][k];
      const float4 bv = *(const float4*)&ws[k][tx << 2];
      b[0] = bv.x; b[1] = bv.y; b[2] = bv.z; b[3] = bv.w;
      fma16(a, b, acc);
    }
    __syncthreads();
  }
  const float4 bb = *(const float4*)(b1 + (tx << 2));
  const float bbv[4] = {bb.x, bb.y, bb.z, bb.w};
#pragma unroll
  for (int ii = 0; ii < 4; ++ii) {
    float4 o;
    o.x = fmaxf(acc[ii][0] + bbv[0], 0.f);
    o.y = fmaxf(acc[ii][1] + bbv[1], 0.f);
    o.z = fmaxf(acc[ii][2] + bbv[2], 0.f);
    o.w = fmaxf(acc[ii][3] + bbv[3], 0.f);
    *(float4*)(h + (row0 + (ty << 2) + ii) * H_ + (tx << 2)) = o;
  }
}

// ---------------- K2: e_t[c][row] = (h @ w2 + b2)^T ----------------
// grid B_/64 x 256
__global__ __launch_bounds__(256)
void enc2_kernel(const float* __restrict__ h, const float* __restrict__ w2,
                 const float* __restrict__ b2, float* __restrict__ e_t) {
  __shared__ float hs[64][64];   // [r][k]
  __shared__ float ws[64][64];   // [k][c]
  const int t = threadIdx.x;
  const int tx = t & 15, ty = t >> 4;
  const long row0 = (long)blockIdx.x * 64;
#pragma unroll
  for (int i = 0; i < 4; ++i) {
    const int r = ty + 16 * i;
    *(float4*)&hs[r][tx << 2] = *(const float4*)(h + (row0 + r) * H_ + (tx << 2));
  }
  for (int c0 = 0; c0 < L_; c0 += 64) {
#pragma unroll
    for (int i = 0; i < 4; ++i) {
      const int g = (i << 8) + t;
      const int kk = g >> 4, c = (g & 15) << 2;
      *(float4*)&ws[kk][c] = *(const float4*)(w2 + (long)kk * L_ + c0 + c);
    }
    __syncthreads();
    float acc[4][4] = {};
#pragma unroll 4
    for (int k = 0; k < 64; ++k) {
      float a[4], b[4];
#pragma unroll
      for (int ii = 0; ii < 4; ++ii) a[ii] = hs[(ty << 2) + ii][k];
      const float4 bv = *(const float4*)&ws[k][tx << 2];
      b[0] = bv.x; b[1] = bv.y; b[2] = bv.z; b[3] = bv.w;
      fma16(a, b, acc);
    }
#pragma unroll
    for (int jj = 0; jj < 4; ++jj) {
      const int c = c0 + (tx << 2) + jj;
      const float bias = b2[c];
#pragma unroll
      for (int ii = 0; ii < 4; ++ii)
        e_t[(long)c * B_ + row0 + (ty << 2) + ii] = acc[ii][jj] + bias;
    }
    __syncthreads();
  }
}

// ---------------- K3: fused distance + argmin ----------------
// score[r][c] = ||emb_c||^2 - 2 e_r . emb_c  (||e||^2 dropped: row-constant)
// grid (B_/64, 4) x 256; each block: 64 rows x 1024 codes
__global__ __launch_bounds__(256)
void dist_kernel(const float* __restrict__ e_t, const float* __restrict__ embT,
                 const float* __restrict__ wnorm, unsigned long long* __restrict__ keys) {
  __shared__ float smem[2 * 64 * 64];   // es [l][r] | bs [l][c], stride 64
  float* es = smem;
  float* bs = smem + 4096;
  const int t = threadIdx.x;
  const int tx = t & 15, ty = t >> 4;
  const long row0 = (long)blockIdx.x * 64;
  const int cbase = blockIdx.y * (K_ / 4);
  unsigned long long best[4] = {~0ull, ~0ull, ~0ull, ~0ull};

  for (int cc = 0; cc < K_ / 4; cc += 64) {
    float acc[4][4] = {};
    for (int l0 = 0; l0 < L_; l0 += 64) {
#pragma unroll
      for (int i = 0; i < 4; ++i) {
        const int g = (i << 8) + t;
        const int l = g >> 4, col = (g & 15) << 2;
        *(float4*)&es[l * 64 + col] = *(const float4*)(e_t + (long)(l0 + l) * B_ + row0 + col);
        *(float4*)&bs[l * 64 + col] = *(const float4*)(embT + (long)(l0 + l) * K_ + cbase + cc + col);
      }
      __syncthreads();
#pragma unroll 4
      for (int l = 0; l < 64; ++l) {
        float a[4], b[4];
        const float4 av = *(const float4*)&es[l * 64 + (ty << 2)];
        a[0] = av.x; a[1] = av.y; a[2] = av.z; a[3] = av.w;
        const float4 bv = *(const float4*)&bs[l * 64 + (tx << 2)];
        b[0] = bv.x; b[1] = bv.y; b[2] = bv.z; b[3] = bv.w;
        fma16(a, b, acc);
      }
      __syncthreads();
    }
#pragma unroll
    for (int jj = 0; jj < 4; ++jj) {
      const int c = cbase + cc + (tx << 2) + jj;
      const float wn = wnorm[c];
#pragma unroll
      for (int ii = 0; ii < 4; ++ii) {
        const float score = fmaf(-2.f, acc[ii][jj], wn);
        const unsigned long long key =
            ((unsigned long long)f2ord(score) << 32) | (unsigned int)c;
        best[ii] = key < best[ii] ? key : best[ii];
      }
    }
  }
  __syncthreads();
  unsigned long long* red = (unsigned long long*)smem;  // [64][16], overlays es
#pragma unroll
  for (int ii = 0; ii < 4; ++ii) red[((ty << 2) + ii) * 16 + tx] = best[ii];
  __syncthreads();
  if (t < 64) {
    unsigned long long m = red[t * 16];
#pragma unroll
    for (int q = 1; q < 16; ++q) {
      const unsigned long long v = red[t * 16 + q];
      m = v < m ? v : m;
    }
    atomicMin(&keys[row0 + t], m);
  }
}

// ---------------- K4: decoder ----------------
// grid B_/64 x 256
__global__ __launch_bounds__(256)
void dec_kernel(const unsigned long long* __restrict__ keys, const float* __restrict__ emb,
                const float* __restrict__ w1, const float* __restrict__ b1,
                const float* __restrict__ w2, const float* __restrict__ b2,
                float* __restrict__ out) {
  __shared__ float zs[64][64];   // [r][l] chunk
  __shared__ float w1s[64][64];  // [l][j]
  __shared__ float gt[64][64];   // [j][r]
  __shared__ float w2s[64][64];  // [j][s]
  __shared__ int idxs[64];
  const int t = threadIdx.x;
  const int tx = t & 15, ty = t >> 4;
  const long row0 = (long)blockIdx.x * 64;
  if (t < 64) idxs[t] = (int)(keys[row0 + t] & 0xFFFFFFFFull);
  __syncthreads();

  float acc[4][4] = {};
  for (int l0 = 0; l0 < L_; l0 += 64) {
#pragma unroll
    for (int i = 0; i < 4; ++i) {
      const int r = ty + 16 * i;
      const long zrow = (long)idxs[r] * L_;
      *(float4*)&zs[r][tx << 2] = *(const float4*)(emb + zrow + l0 + (tx << 2));
    }
#pragma unroll
    for (int i = 0; i < 4; ++i) {
      const int g = (i << 8) + t;
      const int kk = g >> 4, c = (g & 15) << 2;
      *(float4*)&w1s[kk][c] = *(const float4*)(w1 + (long)(l0 + kk) * H_ + c);
    }
    __syncthreads();
#pragma unroll 4
    for (int k = 0; k < 64; ++k) {
      float a[4], b[4];
#pragma unroll
      for (int ii = 0; ii < 4; ++ii) a[ii] = zs[(ty << 2) + ii][k];
      const float4 bv = *(const float4*)&w1s[k][tx << 2];
      b[0] = bv.x; b[1] = bv.y; b[2] = bv.z; b[3] = bv.w;
      fma16(a, b, acc);
    }
    __syncthreads();
  }
  // g = relu(acc + b1), stored transposed gt[j][r]
#pragma unroll
  for (int jj = 0; jj < 4; ++jj) {
    const float bias = b1[(tx << 2) + jj];
#pragma unroll
    for (int ii = 0; ii < 4; ++ii)
      gt[(tx << 2) + jj][(ty << 2) + ii] = fmaxf(acc[ii][jj] + bias, 0.f);
  }

  for (int s0 = 0; s0 < S_; s0 += 64) {
#pragma unroll
    for (int i = 0; i < 4; ++i) {
      const int g = (i << 8) + t;
      const int j = g >> 4, s = (g & 15) << 2;
      *(float4*)&w2s[j][s] = *(const float4*)(w2 + (long)j * S_ + s0 + s);
    }
    __syncthreads();
    float a2[4][4] = {};
#pragma unroll 4
    for (int j = 0; j < 64; ++j) {
      float a[4], b[4];
      const float4 av = *(const float4*)&gt[j][ty << 2];
      a[0] = av.x; a[1] = av.y; a[2] = av.z; a[3] = av.w;
      const float4 bv = *(const float4*)&w2s[j][tx << 2];
      b[0] = bv.x; b[1] = bv.y; b[2] = bv.z; b[3] = bv.w;
      fma16(a, b, a2);
    }
    __syncthreads();
    const float4 bb = *(const float4*)(b2 + s0 + (tx << 2));
#pragma unroll
    for (int ii = 0; ii < 4; ++ii) {
      float4 o;
      o.x = a2[ii][0] + bb.x;
      o.y = a2[ii][1] + bb.y;
      o.z = a2[ii][2] + bb.z;
      o.w = a2[ii][3] + bb.w;
      *(float4*)(out + (row0 + (ty << 2) + ii) * S_ + s0 + (tx << 2)) = o;
    }
  }
}

extern "C" void kernel_launch(void* const* d_in, const int* in_sizes, int n_in,
                              void* d_out, int out_size, void* d_ws, size_t ws_size,
                              hipStream_t stream) {
  (void)in_sizes; (void)n_in; (void)out_size; (void)ws_size;
  const float* x      = (const float*)d_in[0];
  const float* enc_w1 = (const float*)d_in[1];
  const float* enc_b1 = (const float*)d_in[2];
  const float* enc_w2 = (const float*)d_in[3];
  const float* enc_b2 = (const float*)d_in[4];
  const float* emb    = (const float*)d_in[5];
  const float* dec_w1 = (const float*)d_in[6];
  const float* dec_b1 = (const float*)d_in[7];
  const float* dec_w2 = (const float*)d_in[8];
  const float* dec_b2 = (const float*)d_in[9];
  float* out = (float*)d_out;

  char* p = (char*)d_ws;
  float* h    = (float*)p;  p += (size_t)B_ * H_ * 4;   // 4 MB
  float* e_t  = (float*)p;  p += (size_t)L_ * B_ * 4;   // 16 MB
  float* embT = (float*)p;  p += (size_t)L_ * K_ * 4;   // 4 MB
  float* wnrm = (float*)p;  p += (size_t)K_ * 4;        // 16 KB
  unsigned long long* keys = (unsigned long long*)p;    // 128 KB

  hipMemsetAsync(keys, 0xFF, (size_t)B_ * 8, stream);
  wnorm_kernel<<<K_ / 4, 256, 0, stream>>>(emb, wnrm);
  tr_emb_kernel<<<dim3(K_ / 64, L_ / 64), 256, 0, stream>>>(emb, embT);
  enc1_kernel<<<B_ / 64, 256, 0, stream>>>(x, enc_w1, enc_b1, h);
  enc2_kernel<<<B_ / 64, 256, 0, stream>>>(h, enc_w2, enc_b2, e_t);
  dist_kernel<<<dim3(B_ / 64, 4), 256, 0, stream>>>(e_t, embT, wnrm, keys);
  dec_kernel<<<B_ / 64, 256, 0, stream>>>(keys, emb, dec_w1, dec_b1, dec_w2, dec_b2, out);
}

// Round 2
// 499.970 us; speedup vs baseline: 1.5317x; 1.5317x over previous
//
#include <hip/hip_runtime.h>
#include <cstdint>

#define B_ 16384
#define S_ 1024
#define L_ 256
#define K_ 4096
#define H_ 64
#define TAU 0.02f

typedef __attribute__((ext_vector_type(8))) short short8;
typedef __attribute__((ext_vector_type(4))) float floatx4;

#define AS1 __attribute__((address_space(1)))
#define AS3 __attribute__((address_space(3)))

__device__ __forceinline__ unsigned int f2ord(float f) {
  unsigned int u = __float_as_uint(f);
  return (u & 0x80000000u) ? ~u : (u | 0x80000000u);
}
__device__ __forceinline__ float ord2f(unsigned int o) {
  unsigned int u = (o & 0x80000000u) ? (o ^ 0x80000000u) : ~o;
  return __uint_as_float(u);
}
// round-to-nearest-even fp32 -> bf16
__device__ __forceinline__ unsigned short bf16rne(float f, float* hif) {
  unsigned int u = __float_as_uint(f);
  unsigned int r = (u + 0x7fffu + ((u >> 16) & 1u)) >> 16;
  *hif = __uint_as_float(r << 16);
  return (unsigned short)r;
}
__device__ __forceinline__ void bf16split(float f, unsigned short* hi, unsigned short* lo) {
  float hif, d;
  *hi = bf16rne(f, &hif);
  *lo = bf16rne(f - hif, &d);
}

__device__ __forceinline__ void fma16(const float a[4], const float b[4], float acc[4][4]) {
#pragma unroll
  for (int ii = 0; ii < 4; ++ii)
#pragma unroll
    for (int jj = 0; jj < 4; ++jj)
      acc[ii][jj] = fmaf(a[ii], b[jj], acc[ii][jj]);
}

// ---------------- K0a: wnorm[c] = ||emb[c]||^2 ----------------
__global__ __launch_bounds__(256)
void wnorm_kernel(const float* __restrict__ emb, float* __restrict__ wnorm) {
  const int lane = threadIdx.x & 63, wv = threadIdx.x >> 6;
  const int c = blockIdx.x * 4 + wv;
  const float4 v = *(const float4*)(emb + (long)c * L_ + (lane << 2));
  float s = v.x * v.x + v.y * v.y + v.z * v.z + v.w * v.w;
#pragma unroll
  for (int off = 32; off > 0; off >>= 1) s += __shfl_down(s, off, 64);
  if (lane == 0) wnorm[c] = s;
}

// ---------------- K0b: emb -> bf16 hi/lo ----------------
__global__ __launch_bounds__(256)
void cvt_emb_kernel(const float* __restrict__ emb, unsigned short* __restrict__ hi,
                    unsigned short* __restrict__ lo) {
  const size_t i = ((size_t)blockIdx.x * 256 + threadIdx.x) * 4;
  const float4 v = *(const float4*)(emb + i);
  ushort4 hv, lv;
  bf16split(v.x, &hv.x, &lv.x);
  bf16split(v.y, &hv.y, &lv.y);
  bf16split(v.z, &hv.z, &lv.z);
  bf16split(v.w, &hv.w, &lv.w);
  *(ushort4*)(hi + i) = hv;
  *(ushort4*)(lo + i) = lv;
}

// ---------------- K1: h = relu(x @ w1 + b1) ----------------
__global__ __launch_bounds__(256)
void enc1_kernel(const float* __restrict__ x, const float* __restrict__ w1,
                 const float* __restrict__ b1, float* __restrict__ h) {
  __shared__ float xs[64][64];
  __shared__ float ws[64][64];
  const int t = threadIdx.x;
  const int tx = t & 15, ty = t >> 4;
  const long row0 = (long)blockIdx.x * 64;
  float acc[4][4] = {};
  for (int k0 = 0; k0 < S_; k0 += 64) {
#pragma unroll
    for (int i = 0; i < 4; ++i) {
      const int r = ty + 16 * i;
      *(float4*)&xs[r][tx << 2] = *(const float4*)(x + (row0 + r) * S_ + k0 + (tx << 2));
    }
#pragma unroll
    for (int i = 0; i < 4; ++i) {
      const int g = (i << 8) + t;
      const int kk = g >> 4, c = (g & 15) << 2;
      *(float4*)&ws[kk][c] = *(const float4*)(w1 + (long)(k0 + kk) * H_ + c);
    }
    __syncthreads();
#pragma unroll 4
    for (int k = 0; k < 64; ++k) {
      float a[4], b[4];
#pragma unroll
      for (int ii = 0; ii < 4; ++ii) a[ii] = xs[(ty << 2) + ii][k];
      const float4 bv = *(const float4*)&ws[k][tx << 2];
      b[0] = bv.x; b[1] = bv.y; b[2] = bv.z; b[3] = bv.w;
      fma16(a, b, acc);
    }
    __syncthreads();
  }
  const float4 bb = *(const float4*)(b1 + (tx << 2));
  const float bbv[4] = {bb.x, bb.y, bb.z, bb.w};
#pragma unroll
  for (int ii = 0; ii < 4; ++ii) {
    float4 o;
    o.x = fmaxf(acc[ii][0] + bbv[0], 0.f);
    o.y = fmaxf(acc[ii][1] + bbv[1], 0.f);
    o.z = fmaxf(acc[ii][2] + bbv[2], 0.f);
    o.w = fmaxf(acc[ii][3] + bbv[3], 0.f);
    *(float4*)(h + (row0 + (ty << 2) + ii) * H_ + (tx << 2)) = o;
  }
}

// ---------------- K2: e = h @ w2 + b2 (fp32 + bf16 hi/lo, natural [B][L]) ----------------
__global__ __launch_bounds__(256)
void enc2_kernel(const float* __restrict__ h, const float* __restrict__ w2,
                 const float* __restrict__ b2, float* __restrict__ e32,
                 unsigned short* __restrict__ e_hi, unsigned short* __restrict__ e_lo) {
  __shared__ float hs[64][64];
  __shared__ float ws[64][64];
  const int t = threadIdx.x;
  const int tx = t & 15, ty = t >> 4;
  const long row0 = (long)blockIdx.x * 64;
#pragma unroll
  for (int i = 0; i < 4; ++i) {
    const int r = ty + 16 * i;
    *(float4*)&hs[r][tx << 2] = *(const float4*)(h + (row0 + r) * H_ + (tx << 2));
  }
  for (int c0 = 0; c0 < L_; c0 += 64) {
#pragma unroll
    for (int i = 0; i < 4; ++i) {
      const int g = (i << 8) + t;
      const int kk = g >> 4, c = (g & 15) << 2;
      *(float4*)&ws[kk][c] = *(const float4*)(w2 + (long)kk * L_ + c0 + c);
    }
    __syncthreads();
    float acc[4][4] = {};
#pragma unroll 4
    for (int k = 0; k < 64; ++k) {
      float a[4], b[4];
#pragma unroll
      for (int ii = 0; ii < 4; ++ii) a[ii] = hs[(ty << 2) + ii][k];
      const float4 bv = *(const float4*)&ws[k][tx << 2];
      b[0] = bv.x; b[1] = bv.y; b[2] = bv.z; b[3] = bv.w;
      fma16(a, b, acc);
    }
    const float4 bb = *(const float4*)(b2 + c0 + (tx << 2));
#pragma unroll
    for (int ii = 0; ii < 4; ++ii) {
      const long row = row0 + (ty << 2) + ii;
      float4 o;
      o.x = acc[ii][0] + bb.x;
      o.y = acc[ii][1] + bb.y;
      o.z = acc[ii][2] + bb.z;
      o.w = acc[ii][3] + bb.w;
      *(float4*)(e32 + row * L_ + c0 + (tx << 2)) = o;
      ushort4 hv, lv;
      bf16split(o.x, &hv.x, &lv.x);
      bf16split(o.y, &hv.y, &lv.y);
      bf16split(o.z, &hv.z, &lv.z);
      bf16split(o.w, &hv.w, &lv.w);
      *(ushort4*)(e_hi + row * L_ + c0 + (tx << 2)) = hv;
      *(ushort4*)(e_lo + row * L_ + c0 + (tx << 2)) = lv;
    }
    __syncthreads();
  }
}

// ---------------- K3: MFMA split-bf16 distance + per-row top-2 ----------------
// grid (B_/128, 8). Block: 128 rows x (4 tiles of 128 codes). 3 MFMAs per k-step.
__global__ __launch_bounds__(256)
void distb_kernel(const unsigned short* __restrict__ emb_hi, const unsigned short* __restrict__ emb_lo,
                  const unsigned short* __restrict__ e_hi, const unsigned short* __restrict__ e_lo,
                  const float* __restrict__ wnorm, unsigned long long* __restrict__ part) {
  __shared__ char smem[4 * 8192];
  __shared__ float wnorm_s[128];
  const int t = threadIdx.x;
  const int lane = t & 63, wv = t >> 6;
  const int wm = wv >> 1, wn = wv & 1;
  const int n0 = blockIdx.x * 128;

  // staging lane constants (16B-quarter rotation swizzle, s(r) = (r + r/4) & 3 on r&15)
  const int lr = lane >> 2;                         // dest row within a 16-row issue
  const int sst = (lr + (lane >> 4)) & 3;           // s(lr)
  const int qsrc = ((lane & 3) - sst) & 3;          // logical source quarter
  const size_t lane_goff = (size_t)lr * (L_ * 2) + (size_t)qsrc * 16;

  // fragment-read lane constants
  const int ln = lane & 15, quad = lane >> 4;
  const int sfr = (ln + (ln >> 2)) & 3;
  const int qp = (quad + sfr) & 3;                  // physical quarter for logical quad

  char* const sAhi = smem;
  char* const sAlo = smem + 8192;
  char* const sBhi = smem + 16384;
  char* const sBlo = smem + 24576;
  char* const myTile = smem + wv * 8192;

  unsigned long long b1[4] = {~0ull, ~0ull, ~0ull, ~0ull};
  unsigned long long b2[4] = {~0ull, ~0ull, ~0ull, ~0ull};

  for (int mt = 0; mt < 4; ++mt) {
    const int m0 = (blockIdx.y * 4 + mt) * 128;
    const char* gbase;
    if (wv == 0)      gbase = (const char*)emb_hi + (size_t)m0 * L_ * 2;
    else if (wv == 1) gbase = (const char*)emb_lo + (size_t)m0 * L_ * 2;
    else if (wv == 2) gbase = (const char*)e_hi + (size_t)n0 * L_ * 2;
    else              gbase = (const char*)e_lo + (size_t)n0 * L_ * 2;

    floatx4 acc[4][4];
#pragma unroll
    for (int a = 0; a < 4; ++a)
#pragma unroll
      for (int b = 0; b < 4; ++b) acc[a][b] = (floatx4){0.f, 0.f, 0.f, 0.f};

    for (int kc = 0; kc < 8; ++kc) {
      const char* gsrc = gbase + (size_t)(kc * 64) + lane_goff;  // kc*32 elems * 2B
#pragma unroll
      for (int j = 0; j < 8; ++j) {
        __builtin_amdgcn_global_load_lds((const AS1 void*)(gsrc + (size_t)j * (16 * L_ * 2)),
                                         (AS3 void*)(myTile + j * 1024), 16, 0, 0);
      }
      __syncthreads();
      short8 ahi[4], alo[4], bhi[4], blo[4];
#pragma unroll
      for (int mf = 0; mf < 4; ++mf) {
        const int rb = (wm * 64 + mf * 16 + ln) * 64 + qp * 16;
        ahi[mf] = *(const short8*)(sAhi + rb);
        alo[mf] = *(const short8*)(sAlo + rb);
      }
#pragma unroll
      for (int nf = 0; nf < 4; ++nf) {
        const int rb = (wn * 64 + nf * 16 + ln) * 64 + qp * 16;
        bhi[nf] = *(const short8*)(sBhi + rb);
        blo[nf] = *(const short8*)(sBlo + rb);
      }
#pragma unroll
      for (int mf = 0; mf < 4; ++mf)
#pragma unroll
        for (int nf = 0; nf < 4; ++nf) {
          acc[mf][nf] = __builtin_amdgcn_mfma_f32_16x16x32_bf16(ahi[mf], bhi[nf], acc[mf][nf], 0, 0, 0);
          acc[mf][nf] = __builtin_amdgcn_mfma_f32_16x16x32_bf16(ahi[mf], blo[nf], acc[mf][nf], 0, 0, 0);
          acc[mf][nf] = __builtin_amdgcn_mfma_f32_16x16x32_bf16(alo[mf], bhi[nf], acc[mf][nf], 0, 0, 0);
        }
      __syncthreads();
    }
    if (t < 128) wnorm_s[t] = wnorm[m0 + t];
    __syncthreads();
#pragma unroll
    for (int nf = 0; nf < 4; ++nf) {
#pragma unroll
      for (int mf = 0; mf < 4; ++mf) {
#pragma unroll
        for (int rr = 0; rr < 4; ++rr) {
          const int ml = wm * 64 + mf * 16 + quad * 4 + rr;
          const float score = fmaf(-2.f, acc[mf][nf][rr], wnorm_s[ml]);
          const unsigned long long key =
              ((unsigned long long)f2ord(score) << 32) | (unsigned int)(m0 + ml);
          if (key < b1[nf]) { b2[nf] = b1[nf]; b1[nf] = key; }
          else if (key < b2[nf]) b2[nf] = key;
        }
      }
    }
    __syncthreads();
  }
  // merge top-2 across lanes sharing the same batch row (xor 16, 32)
#pragma unroll
  for (int d = 16; d <= 32; d <<= 1) {
#pragma unroll
    for (int nf = 0; nf < 4; ++nf) {
      const unsigned long long o1 = __shfl_xor(b1[nf], d, 64);
      const unsigned long long o2 = __shfl_xor(b2[nf], d, 64);
      const unsigned long long n1 = o1 < b1[nf] ? o1 : b1[nf];
      const unsigned long long hm = o1 < b1[nf] ? b1[nf] : o1;
      const unsigned long long l2 = o2 < b2[nf] ? o2 : b2[nf];
      b1[nf] = n1;
      b2[nf] = hm < l2 ? hm : l2;
    }
  }
  if (lane < 16) {
    const int slice = blockIdx.y * 2 + wm;
#pragma unroll
    for (int nf = 0; nf < 4; ++nf) {
      const int row = n0 + wn * 64 + nf * 16 + lane;
      const size_t slot = ((size_t)slice * B_ + row) * 2;
      part[slot] = b1[nf];
      part[slot + 1] = b2[nf];
    }
  }
}

// ---------------- K4: merge partials, flag small-gap rows ----------------
__global__ __launch_bounds__(256)
void finalize_kernel(const unsigned long long* __restrict__ part, int* __restrict__ idx,
                     int* __restrict__ flagged, int* __restrict__ counter) {
  const int row = blockIdx.x * 256 + threadIdx.x;
  unsigned long long b1 = ~0ull, b2 = ~0ull;
#pragma unroll
  for (int s = 0; s < 16; ++s) {
    const unsigned long long o1 = part[((size_t)s * B_ + row) * 2];
    const unsigned long long o2 = part[((size_t)s * B_ + row) * 2 + 1];
    const unsigned long long n1 = o1 < b1 ? o1 : b1;
    const unsigned long long hm = o1 < b1 ? b1 : o1;
    const unsigned long long l2 = o2 < b2 ? o2 : b2;
    b1 = n1;
    b2 = hm < l2 ? hm : l2;
  }
  idx[row] = (int)(b1 & 0xffffffffull);
  const float s1 = ord2f((unsigned int)(b1 >> 32));
  const float s2 = ord2f((unsigned int)(b2 >> 32));
  if (s2 - s1 < TAU) {
    const int p = atomicAdd(counter, 1);
    flagged[p] = row;
  }
}

// ---------------- K5: exact fp32 recheck of flagged rows ----------------
__global__ __launch_bounds__(256)
void recheck_kernel(const int* __restrict__ counter, const int* __restrict__ flagged,
                    const float* __restrict__ e32, const float* __restrict__ emb,
                    const float* __restrict__ wnorm, int* __restrict__ idx) {
  __shared__ float er[L_];
  __shared__ unsigned long long red[4];
  const int t = threadIdx.x;
  const int lane = t & 63, wv = t >> 6;
  const int n = *counter;
  for (int i = blockIdx.x; i < n; i += gridDim.x) {
    const int row = flagged[i];
    __syncthreads();
    er[t] = e32[(size_t)row * L_ + t];
    __syncthreads();
    unsigned long long best = ~0ull;
    for (int c = t; c < K_; c += 256) {
      const float4* wr = (const float4*)(emb + (size_t)c * L_);
      float dot = 0.f;
#pragma unroll 8
      for (int l = 0; l < L_ / 4; ++l) {
        const float4 w = wr[l];
        dot = fmaf(w.x, er[4 * l], dot);
        dot = fmaf(w.y, er[4 * l + 1], dot);
        dot = fmaf(w.z, er[4 * l + 2], dot);
        dot = fmaf(w.w, er[4 * l + 3], dot);
      }
      const float score = fmaf(-2.f, dot, wnorm[c]);
      const unsigned long long key = ((unsigned long long)f2ord(score) << 32) | (unsigned int)c;
      best = key < best ? key : best;
    }
#pragma unroll
    for (int off = 32; off > 0; off >>= 1) {
      const unsigned long long o = __shfl_down(best, off, 64);
      best = o < best ? o : best;
    }
    if (lane == 0) red[wv] = best;
    __syncthreads();
    if (t == 0) {
      unsigned long long m = red[0];
#pragma unroll
      for (int q = 1; q < 4; ++q) m = red[q] < m ? red[q] : m;
      idx[row] = (int)(m & 0xffffffffull);
    }
  }
}

// ---------------- K6: decoder ----------------
__global__ __launch_bounds__(256)
void dec_kernel(const int* __restrict__ idx, const float* __restrict__ emb,
                const float* __restrict__ w1, const float* __restrict__ b1,
                const float* __restrict__ w2, const float* __restrict__ b2,
                float* __restrict__ out) {
  __shared__ float zs[64][64];
  __shared__ float w1s[64][64];
  __shared__ float gt[64][64];
  __shared__ float w2s[64][64];
  __shared__ int idxs[64];
  const int t = threadIdx.x;
  const int tx = t & 15, ty = t >> 4;
  const long row0 = (long)blockIdx.x * 64;
  if (t < 64) idxs[t] = idx[row0 + t];
  __syncthreads();

  float acc[4][4] = {};
  for (int l0 = 0; l0 < L_; l0 += 64) {
#pragma unroll
    for (int i = 0; i < 4; ++i) {
      const int r = ty + 16 * i;
      const long zrow = (long)idxs[r] * L_;
      *(float4*)&zs[r][tx << 2] = *(const float4*)(emb + zrow + l0 + (tx << 2));
    }
#pragma unroll
    for (int i = 0; i < 4; ++i) {
      const int g = (i << 8) + t;
      const int kk = g >> 4, c = (g & 15) << 2;
      *(float4*)&w1s[kk][c] = *(const float4*)(w1 + (long)(l0 + kk) * H_ + c);
    }
    __syncthreads();
#pragma unroll 4
    for (int k = 0; k < 64; ++k) {
      float a[4], b[4];
#pragma unroll
      for (int ii = 0; ii < 4; ++ii) a[ii] = zs[(ty << 2) + ii][k];
      const float4 bv = *(const float4*)&w1s[k][tx << 2];
      b[0] = bv.x; b[1] = bv.y; b[2] = bv.z; b[3] = bv.w;
      fma16(a, b, acc);
    }
    __syncthreads();
  }
#pragma unroll
  for (int jj = 0; jj < 4; ++jj) {
    const float bias = b1[(tx << 2) + jj];
#pragma unroll
    for (int ii = 0; ii < 4; ++ii)
      gt[(tx << 2) + jj][(ty << 2) + ii] = fmaxf(acc[ii][jj] + bias, 0.f);
  }

  for (int s0 = 0; s0 < S_; s0 += 64) {
#pragma unroll
    for (int i = 0; i < 4; ++i) {
      const int g = (i << 8) + t;
      const int j = g >> 4, s = (g & 15) << 2;
      *(float4*)&w2s[j][s] = *(const float4*)(w2 + (long)j * S_ + s0 + s);
    }
    __syncthreads();
    float a2[4][4] = {};
#pragma unroll 4
    for (int j = 0; j < 64; ++j) {
      float a[4], b[4];
      const float4 av = *(const float4*)&gt[j][ty << 2];
      a[0] = av.x; a[1] = av.y; a[2] = av.z; a[3] = av.w;
      const float4 bv = *(const float4*)&w2s[j][tx << 2];
      b[0] = bv.x; b[1] = bv.y; b[2] = bv.z; b[3] = bv.w;
      fma16(a, b, a2);
    }
    __syncthreads();
    const float4 bb = *(const float4*)(b2 + s0 + (tx << 2));
#pragma unroll
    for (int ii = 0; ii < 4; ++ii) {
      float4 o;
      o.x = a2[ii][0] + bb.x;
      o.y = a2[ii][1] + bb.y;
      o.z = a2[ii][2] + bb.z;
      o.w = a2[ii][3] + bb.w;
      *(float4*)(out + (row0 + (ty << 2) + ii) * S_ + s0 + (tx << 2)) = o;
    }
  }
}

extern "C" void kernel_launch(void* const* d_in, const int* in_sizes, int n_in,
                              void* d_out, int out_size, void* d_ws, size_t ws_size,
                              hipStream_t stream) {
  (void)in_sizes; (void)n_in; (void)out_size; (void)ws_size;
  const float* x      = (const float*)d_in[0];
  const float* enc_w1 = (const float*)d_in[1];
  const float* enc_b1 = (const float*)d_in[2];
  const float* enc_w2 = (const float*)d_in[3];
  const float* enc_b2 = (const float*)d_in[4];
  const float* emb    = (const float*)d_in[5];
  const float* dec_w1 = (const float*)d_in[6];
  const float* dec_b1 = (const float*)d_in[7];
  const float* dec_w2 = (const float*)d_in[8];
  const float* dec_b2 = (const float*)d_in[9];
  float* out = (float*)d_out;

  char* p = (char*)d_ws;
  float* h    = (float*)p;          p += (size_t)B_ * H_ * 4;   // 4 MB
  float* e32  = (float*)p;          p += (size_t)B_ * L_ * 4;   // 16 MB
  unsigned short* e_hi = (unsigned short*)p;   p += (size_t)B_ * L_ * 2;  // 8 MB
  unsigned short* e_lo = (unsigned short*)p;   p += (size_t)B_ * L_ * 2;  // 8 MB
  unsigned short* emb_hi = (unsigned short*)p; p += (size_t)K_ * L_ * 2;  // 2 MB
  unsigned short* emb_lo = (unsigned short*)p; p += (size_t)K_ * L_ * 2;  // 2 MB
  float* wnrm = (float*)p;          p += (size_t)K_ * 4;        // 16 KB
  unsigned long long* part = (unsigned long long*)p; p += (size_t)16 * B_ * 2 * 8;  // 4 MB
  int* idx     = (int*)p;           p += (size_t)B_ * 4;        // 64 KB
  int* flagged = (int*)p;           p += (size_t)B_ * 4;        // 64 KB
  int* counter = (int*)p;           p += 256;

  hipMemsetAsync(counter, 0, 4, stream);
  wnorm_kernel<<<K_ / 4, 256, 0, stream>>>(emb, wnrm);
  cvt_emb_kernel<<<(K_ * L_) / 1024, 256, 0, stream>>>(emb, emb_hi, emb_lo);
  enc1_kernel<<<B_ / 64, 256, 0, stream>>>(x, enc_w1, enc_b1, h);
  enc2_kernel<<<B_ / 64, 256, 0, stream>>>(h, enc_w2, enc_b2, e32, e_hi, e_lo);
  distb_kernel<<<dim3(B_ / 128, 8), 256, 0, stream>>>(emb_hi, emb_lo, e_hi, e_lo, wnrm, part);
  finalize_kernel<<<B_ / 256, 256, 0, stream>>>(part, idx, flagged, counter);
  recheck_kernel<<<256, 256, 0, stream>>>(counter, flagged, e32, emb, wnrm, idx);
  dec_kernel<<<B_ / 64, 256, 0, stream>>>(idx, emb, dec_w1, dec_b1, dec_w2, dec_b2, out);
}